// Round 1
// baseline (312.328 us; speedup 1.0000x reference)
//
#include <hip/hip_runtime.h>
#include <cstdint>
#include <cstddef>

#define BM 128
#define BN 256
#define BK 64
#define KT_STEPS 12
#define THREADS 512
#define LDS_A_BYTES (BM * BK * 2)                   // 16384
#define LDS_B_BYTES (BN * BK * 2)                   // 32768
#define LDS_BUF_BYTES (LDS_A_BYTES + LDS_B_BYTES)   // 49152
#define LDS_TOTAL (2 * LDS_BUF_BYTES)               // 98304

typedef __attribute__((ext_vector_type(4))) float f32x4;
typedef __attribute__((ext_vector_type(8))) short bf16x8;

__device__ __forceinline__ unsigned short f2bf(float f) {
  union { float f; uint32_t u; } v; v.f = f;
  uint32_t r = v.u + 0x7FFFu + ((v.u >> 16) & 1u);   // round-to-nearest-even
  return (unsigned short)(r >> 16);
}

__device__ __forceinline__ bf16x8 cvt8(f32x4 a, f32x4 b) {
  bf16x8 r;
  r[0] = (short)f2bf(a[0]); r[1] = (short)f2bf(a[1]);
  r[2] = (short)f2bf(a[2]); r[3] = (short)f2bf(a[3]);
  r[4] = (short)f2bf(b[0]); r[5] = (short)f2bf(b[1]);
  r[6] = (short)f2bf(b[2]); r[7] = (short)f2bf(b[3]);
  return r;
}

// W [768][256] f32 -> WtS bf16, layout: row n (0..255) of 768 k, stored as
// 12 chunks of 128B; within each 128B chunk the 16B slots are XOR-swizzled
// with ((n&7)<<4) so the GEMM can global_load_lds LINEARLY and ds_read with
// the same XOR (rule 21: source permutation == read permutation).
__global__ void wt_kernel(const float* __restrict__ W, unsigned short* __restrict__ WtS) {
  const int c8 = blockIdx.x;    // 0..95, chunk of 8 consecutive k
  const int n  = threadIdx.x;   // 0..255
  float v[8];
#pragma unroll
  for (int i = 0; i < 8; ++i) v[i] = W[(size_t)(c8 * 8 + i) * 256 + n];
  f32x4 a = {v[0], v[1], v[2], v[3]};
  f32x4 b = {v[4], v[5], v[6], v[7]};
  size_t off = (size_t)n * 1536 + (size_t)(c8 >> 3) * 128
             + (((c8 & 7) * 16) ^ ((n & 7) << 4));
  *(bf16x8*)((char*)WtS + off) = cvt8(a, b);
}

__global__ __launch_bounds__(THREADS, 2) void edge_gemm(
    const float* __restrict__ srcf, const float* __restrict__ destf,
    const float* __restrict__ eaf, const float* __restrict__ uf,
    const int* __restrict__ batch, const unsigned short* __restrict__ WtS,
    const float* __restrict__ bias, float* __restrict__ out)
{
  extern __shared__ char smem[];
  const int tid  = threadIdx.x;
  const int lane = tid & 63;
  const int w    = tid >> 6;     // wave 0..7
  const int wr   = w >> 2;       // 0..1: 64-row block
  const int wc   = w & 3;        // 0..3: 64-col block
  const int m0   = blockIdx.x * BM;
  const int l15  = lane & 15;
  const int l4   = lane >> 4;

  const int ar = tid >> 2;       // A staging: row 0..127
  const int aq = tid & 3;        // quarter of the 64-float k-slice
  const int ae = m0 + ar;        // edge index for this staging row

  float bs[4];
#pragma unroll
  for (int nf = 0; nf < 4; ++nf) bs[nf] = bias[wc * 64 + nf * 16 + l15];

  f32x4 acc[4][4];
  f32x4 z = {0.f, 0.f, 0.f, 0.f};
#pragma unroll
  for (int i = 0; i < 4; ++i)
#pragma unroll
    for (int j = 0; j < 4; ++j) acc[i][j] = z;

  // which source tensor does K-step kt read from? (concat = [dest,src,ea,u])
  auto a_ptr = [&](int kt) -> const float* {
    const int coff = aq * 16;
    if (kt < 4)  return destf + (size_t)ae * 256 + kt * 64 + coff;
    if (kt < 8)  return srcf  + (size_t)ae * 256 + (kt - 4) * 64 + coff;
    if (kt < 10) return eaf   + (size_t)ae * 128 + (kt - 8) * 64 + coff;
    return uf + (size_t)batch[ae] * 128 + (kt - 10) * 64 + coff;
  };

  f32x4 va0, va1, va2, va3;
  auto load_a = [&](int kt) {
    const float* p = a_ptr(kt);
    va0 = *(const f32x4*)(p);
    va1 = *(const f32x4*)(p + 4);
    va2 = *(const f32x4*)(p + 8);
    va3 = *(const f32x4*)(p + 12);
  };
  auto write_a = [&](int buf) {  // cvt + swizzled ds_write_b128 x2
    char* Ab = smem + buf * LDS_BUF_BYTES;
    const int base = ar * 128;
    const int sw = (ar & 7) << 4;
    *(bf16x8*)(Ab + base + ((aq * 32)      ^ sw)) = cvt8(va0, va1);
    *(bf16x8*)(Ab + base + ((aq * 32 + 16) ^ sw)) = cvt8(va2, va3);
  };
  auto stage_b = [&](int buf, int kt) {  // linear-dest global_load_lds x4
    char* Bb = smem + buf * LDS_BUF_BYTES + LDS_A_BYTES;
    const char* wb = (const char*)WtS + kt * 128;
#pragma unroll
    for (int j = 0; j < 4; ++j) {
      const int chunk = j * 512 + tid;
      const int n = chunk >> 3, c = chunk & 7;
      const char* g = wb + (size_t)n * 1536 + c * 16;
      char* l = Bb + (size_t)(j * 512 + w * 64) * 16;  // wave-uniform base
      __builtin_amdgcn_global_load_lds(
          (const __attribute__((address_space(1))) uint32_t*)g,
          (__attribute__((address_space(3))) uint32_t*)l, 16, 0, 0);
    }
  };
  auto compute = [&](int buf) {
    const char* Ab = smem + buf * LDS_BUF_BYTES;
    const char* Bb = Ab + LDS_A_BYTES;
#pragma unroll
    for (int ks = 0; ks < 2; ++ks) {
      const int kbyte = ks * 64 + l4 * 16;
      bf16x8 af[4], bfr[4];
#pragma unroll
      for (int mf = 0; mf < 4; ++mf) {
        const int r = wr * 64 + mf * 16 + l15;
        af[mf] = *(const bf16x8*)(Ab + r * 128 + (kbyte ^ ((r & 7) << 4)));
      }
#pragma unroll
      for (int nf = 0; nf < 4; ++nf) {
        const int cn = wc * 64 + nf * 16 + l15;
        bfr[nf] = *(const bf16x8*)(Bb + cn * 128 + (kbyte ^ ((cn & 7) << 4)));
      }
#pragma unroll
      for (int mf = 0; mf < 4; ++mf)
#pragma unroll
        for (int nf = 0; nf < 4; ++nf)
          acc[mf][nf] = __builtin_amdgcn_mfma_f32_16x16x32_bf16(
              af[mf], bfr[nf], acc[mf][nf], 0, 0, 0);
    }
  };

  // ---- 2-phase double-buffered K loop ----
  load_a(0);
  stage_b(0, 0);
  write_a(0);
  __syncthreads();

  int cur = 0;
  for (int kt = 0; kt < KT_STEPS; ++kt) {
    const bool more = (kt + 1 < KT_STEPS);
    if (more) {
      load_a(kt + 1);        // issue global loads early
      stage_b(cur ^ 1, kt + 1);
    }
    compute(cur);
    if (more) write_a(cur ^ 1);  // cvt+ds_write after compute (write-late)
    __syncthreads();             // drains vmcnt+lgkmcnt
    cur ^= 1;
  }

  // ---- epilogue: bias + ReLU, C/D layout col=lane&15, row=(lane>>4)*4+j ----
#pragma unroll
  for (int mf = 0; mf < 4; ++mf) {
    const int r0 = m0 + wr * 64 + mf * 16 + l4 * 4;
#pragma unroll
    for (int nf = 0; nf < 4; ++nf) {
      const int cn = wc * 64 + nf * 16 + l15;
      const f32x4 v = acc[mf][nf];
#pragma unroll
      for (int j = 0; j < 4; ++j) {
        const float x = v[j] + bs[nf];
        out[(size_t)(r0 + j) * 256 + cn] = x > 0.f ? x : 0.f;
      }
    }
  }
}

extern "C" void kernel_launch(void* const* d_in, const int* in_sizes, int n_in,
                              void* d_out, int out_size, void* d_ws, size_t ws_size,
                              hipStream_t stream) {
  const float* srcf  = (const float*)d_in[0];
  const float* destf = (const float*)d_in[1];
  const float* eaf   = (const float*)d_in[2];
  const float* uf    = (const float*)d_in[3];
  const int*   batch = (const int*)d_in[4];
  const float* W     = (const float*)d_in[5];
  const float* bias  = (const float*)d_in[6];
  float* out = (float*)d_out;
  unsigned short* WtS = (unsigned short*)d_ws;   // 256*768*2 = 384 KB

  wt_kernel<<<96, 256, 0, stream>>>(W, WtS);

  hipFuncSetAttribute((const void*)edge_gemm,
                      hipFuncAttributeMaxDynamicSharedMemorySize, LDS_TOTAL);
  edge_gemm<<<320000 / BM, THREADS, LDS_TOTAL, stream>>>(
      srcf, destf, eaf, uf, batch, WtS, bias, out);
}

// Round 2
// 258.173 us; speedup vs baseline: 1.2098x; 1.2098x over previous
//
#include <hip/hip_runtime.h>
#include <cstdint>
#include <cstddef>

#define BM 128
#define BN 256
#define BK 32
#define KT_STEPS 24
#define THREADS 512
#define LDS_A_BYTES (BM * BK * 2)                   // 8192
#define LDS_B_BYTES (BN * BK * 2)                   // 16384
#define LDS_BUF_BYTES (LDS_A_BYTES + LDS_B_BYTES)   // 24576
#define LDS_TOTAL (2 * LDS_BUF_BYTES)               // 49152 -> 2 blocks/CU

typedef __attribute__((ext_vector_type(4))) float f32x4;
typedef __attribute__((ext_vector_type(8))) short bf16x8;

__device__ __forceinline__ unsigned short f2bf(float f) {
  union { float f; uint32_t u; } v; v.f = f;
  uint32_t r = v.u + 0x7FFFu + ((v.u >> 16) & 1u);   // round-to-nearest-even
  return (unsigned short)(r >> 16);
}

__device__ __forceinline__ bf16x8 cvt8(f32x4 a, f32x4 b) {
  bf16x8 r;
  r[0] = (short)f2bf(a[0]); r[1] = (short)f2bf(a[1]);
  r[2] = (short)f2bf(a[2]); r[3] = (short)f2bf(a[3]);
  r[4] = (short)f2bf(b[0]); r[5] = (short)f2bf(b[1]);
  r[6] = (short)f2bf(b[2]); r[7] = (short)f2bf(b[3]);
  return r;
}

// WtS: for each K-step kt (24 x 32k), 1024 16B-chunks in EXACTLY the LDS
// order the GEMM wants: chunk c = [colgroup=c>>6][k8=(c>>4)&3][col=c&15],
// holding bf16 W[k0+k8*8 .. +7][colgroup*16+col]. global_load_lds stays
// fully linear (identity permutation on both sides), ds_read_b128 per wave
// covers a contiguous 1KiB slab -> conflict-free.
__global__ void wt_kernel(const float* __restrict__ W, unsigned short* __restrict__ WtS) {
  const int gid = blockIdx.x * 256 + threadIdx.x;   // 0..24575
  const int kt = gid >> 10;
  const int c  = gid & 1023;
  const int n  = ((c >> 6) << 4) | (c & 15);
  const int k0 = kt * 32 + ((c >> 4) & 3) * 8;
  float v[8];
#pragma unroll
  for (int i = 0; i < 8; ++i) v[i] = W[(size_t)(k0 + i) * 256 + n];
  f32x4 a = {v[0], v[1], v[2], v[3]};
  f32x4 b = {v[4], v[5], v[6], v[7]};
  *(bf16x8*)((char*)WtS + (size_t)gid * 16) = cvt8(a, b);
}

__global__ __launch_bounds__(THREADS, 4) void edge_gemm(
    const float* __restrict__ srcf, const float* __restrict__ destf,
    const float* __restrict__ eaf, const float* __restrict__ uf,
    const int* __restrict__ batch, const unsigned short* __restrict__ WtS,
    const float* __restrict__ bias, float* __restrict__ out)
{
  extern __shared__ char smem[];
  const int tid  = threadIdx.x;
  const int lane = tid & 63;
  const int w    = tid >> 6;     // wave 0..7
  const int wr   = w >> 2;       // 0..1: 64-row block
  const int wc   = w & 3;        // 0..3: 64-col block
  const int m0   = blockIdx.x * BM;
  const int l15  = lane & 15;
  const int l4   = lane >> 4;

  const int ar = tid >> 2;       // A staging: row 0..127
  const int aq = tid & 3;        // which 8-float chunk of the 32-float slice
  const int ae = m0 + ar;        // edge index for this staging row

  float bs[4];
#pragma unroll
  for (int nf = 0; nf < 4; ++nf) bs[nf] = bias[wc * 64 + nf * 16 + l15];

  f32x4 acc[4][4];
  f32x4 z = {0.f, 0.f, 0.f, 0.f};
#pragma unroll
  for (int i = 0; i < 4; ++i)
#pragma unroll
    for (int j = 0; j < 4; ++j) acc[i][j] = z;

  // concat = [dest(0..7), src(8..15), edge_attr(16..19), u[batch](20..23)]
  auto a_ptr = [&](int kt) -> const float* {
    const int coff = aq * 8;
    if (kt < 8)  return destf + (size_t)ae * 256 + kt * 32 + coff;
    if (kt < 16) return srcf  + (size_t)ae * 256 + (kt - 8) * 32 + coff;
    if (kt < 20) return eaf   + (size_t)ae * 128 + (kt - 16) * 32 + coff;
    return uf + (size_t)batch[ae] * 128 + (kt - 20) * 32 + coff;
  };

  f32x4 va0, va1;
  auto load_a = [&](int kt) {
    const float* p = a_ptr(kt);
    va0 = *(const f32x4*)(p);
    va1 = *(const f32x4*)(p + 4);
  };
  // A-LDS chunk layout [rowgroup=ar>>4][k8=aq][row=ar&15]: each wave's 64
  // writes land in one contiguous 1KiB slab -> conflict-free.
  auto write_a = [&](int buf) {
    char* Ab = smem + buf * LDS_BUF_BYTES;
    *(bf16x8*)(Ab + (ar >> 4) * 1024 + aq * 256 + (ar & 15) * 16) = cvt8(va0, va1);
  };
  auto stage_b = [&](int buf, int kt) {  // fully linear global_load_lds x2
    char* Bb = smem + buf * LDS_BUF_BYTES + LDS_A_BYTES;
    const char* wb = (const char*)WtS + (size_t)kt * 16384;
#pragma unroll
    for (int j = 0; j < 2; ++j) {
      const char* g = wb + (size_t)(j * 512 + tid) * 16;
      char* l = Bb + (size_t)(j * 512 + w * 64) * 16;  // wave-uniform base
      __builtin_amdgcn_global_load_lds(
          (const __attribute__((address_space(1))) uint32_t*)g,
          (__attribute__((address_space(3))) uint32_t*)l, 16, 0, 0);
    }
  };
  auto compute = [&](int buf) {
    const char* Ab = smem + buf * LDS_BUF_BYTES;
    const char* Bb = Ab + LDS_A_BYTES;
    bf16x8 af[4], bfr[4];
#pragma unroll
    for (int mf = 0; mf < 4; ++mf)   // contiguous 1KiB per wave -> no conflict
      af[mf] = *(const bf16x8*)(Ab + (wr * 4 + mf) * 1024 + l4 * 256 + l15 * 16);
#pragma unroll
    for (int nf = 0; nf < 4; ++nf)
      bfr[nf] = *(const bf16x8*)(Bb + (wc * 4 + nf) * 1024 + l4 * 256 + l15 * 16);
#pragma unroll
    for (int mf = 0; mf < 4; ++mf)
#pragma unroll
      for (int nf = 0; nf < 4; ++nf)
        acc[mf][nf] = __builtin_amdgcn_mfma_f32_16x16x32_bf16(
            af[mf], bfr[nf], acc[mf][nf], 0, 0, 0);
  };

  // ---- 2-phase double-buffered K loop (issue-early / write-late) ----
  load_a(0);
  stage_b(0, 0);
  write_a(0);
  __syncthreads();

  int cur = 0;
  for (int kt = 0; kt < KT_STEPS; ++kt) {
    const bool more = (kt + 1 < KT_STEPS);
    if (more) {
      load_a(kt + 1);            // issue next-step global loads early
      stage_b(cur ^ 1, kt + 1);
    }
    compute(cur);
    if (more) write_a(cur ^ 1);  // cvt + ds_write after compute
    __syncthreads();             // drains vmcnt+lgkmcnt for next step
    cur ^= 1;
  }

  // ---- epilogue: bias + ReLU; C/D layout col=lane&15, row=(lane>>4)*4+j ----
#pragma unroll
  for (int mf = 0; mf < 4; ++mf) {
    const int r0 = m0 + wr * 64 + mf * 16 + l4 * 4;
#pragma unroll
    for (int nf = 0; nf < 4; ++nf) {
      const int cn = wc * 64 + nf * 16 + l15;
      const f32x4 v = acc[mf][nf];
#pragma unroll
      for (int j = 0; j < 4; ++j) {
        const float x = v[j] + bs[nf];
        out[(size_t)(r0 + j) * 256 + cn] = x > 0.f ? x : 0.f;
      }
    }
  }
}

extern "C" void kernel_launch(void* const* d_in, const int* in_sizes, int n_in,
                              void* d_out, int out_size, void* d_ws, size_t ws_size,
                              hipStream_t stream) {
  const float* srcf  = (const float*)d_in[0];
  const float* destf = (const float*)d_in[1];
  const float* eaf   = (const float*)d_in[2];
  const float* uf    = (const float*)d_in[3];
  const int*   batch = (const int*)d_in[4];
  const float* W     = (const float*)d_in[5];
  const float* bias  = (const float*)d_in[6];
  float* out = (float*)d_out;
  unsigned short* WtS = (unsigned short*)d_ws;   // 24*16KB = 384 KB

  wt_kernel<<<96, 256, 0, stream>>>(W, WtS);

  hipFuncSetAttribute((const void*)edge_gemm,
                      hipFuncAttributeMaxDynamicSharedMemorySize, LDS_TOTAL);
  edge_gemm<<<320000 / BM, THREADS, LDS_TOTAL, stream>>>(
      srcf, destf, eaf, uf, batch, WtS, bias, out);
}